// Round 5
// baseline (5054.391 us; speedup 1.0000x reference)
//
#include <hip/hip_runtime.h>
#include <cstddef>

// SNN: 4-layer LIF net, T=200 sequential steps, batch 4096.
// R10: R5-R9 established by ablation that FETCH(8.3GB)/WRITE(85MB) are
// INVARIANT across pinned-VGPR / pinned-AGPR / no-pins-streamed kernels ->
// not spills, and not the proximate wall (hbm_gbps is derived = bytes/dur,
// circular). Direct evidence: MfmaUtil 9%, VALUBusy 8%, 30K cycles/step vs
// ~200 cycles of MFMA issue -> the wall is the 4 serial lds_barrier phases
// per timestep (lockstep latency chains, zero cross-phase overlap).
// Fix: layer-time DIAGONAL PIPELINE. LIF dependence: layer l at time t needs
// only layer l-1 at t and layer l at t-1. So phase p computes L1(p), L2(p-1),
// L3(p-2), L4(p-3) concurrently; every inter-layer dep crosses exactly one
// barrier. 1 barrier/step instead of 4; all layers' L2-loads+MFMAs issue in
// one phase and hide under each other. S1-S3 double-buffered (write [p&1],
// read [p&1^1]). 203 phases with wave-uniform layer guards.
// Each layer's loads/MFMA order copied verbatim from R9 -> absmax 0.
// LDS: Wh1 53,248 + xA 53,248 + 2xS 50,688 = 157,184 B (1 block/CU).
//
// ws layout (_Float16 units): W1hi[256*96] W1lo[256*96] W2hi[256*256]
// W2lo[..] W3hi[..] W3lo[..]  -> 622,592 bytes.

#define BATCH 4096
#define TSTEPS 200
#define NIN 80
#define KP 96
#define NH 256
#define XPAD 104
#define SPAD 264
#define WP1 104   // W1hi LDS row stride: 52 words -> 2-way max on b128

#define W1HI 0
#define W1LO 24576
#define W2HI 49152
#define W2LO 114688
#define W3HI 180224
#define W3LO 245760

#define LO_SCALE 2048.0f
#define LO_INV 4.8828125e-4f

typedef _Float16 h8 __attribute__((ext_vector_type(8)));
typedef float f4 __attribute__((ext_vector_type(4)));

// LDS-only barrier: wait lgkmcnt(0), do NOT drain vmcnt.
// simm16 0xC07F: vmcnt=63 (no wait), expcnt=7 (no wait), lgkmcnt=0.
__device__ __forceinline__ void lds_barrier() {
  __builtin_amdgcn_s_waitcnt(0xC07F);
  __builtin_amdgcn_s_barrier();
}

__global__ __launch_bounds__(256) void prep_kernel(
    const float* __restrict__ W1, const float* __restrict__ W2,
    const float* __restrict__ W3, _Float16* __restrict__ ws) {
  unsigned id = blockIdx.x * 256u + threadIdx.x;
  if (id >= 24576u + 65536u + 65536u) return;
  float v;
  unsigned off;
  _Float16 *hi, *lo;
  if (id < 24576u) {
    unsigned n = id / KP, k = id % KP;
    v = (k < NIN) ? W1[n * NIN + k] : 0.0f;
    hi = ws + W1HI; lo = ws + W1LO; off = id;
  } else if (id < 90112u) {
    off = id - 24576u; v = W2[off];
    hi = ws + W2HI; lo = ws + W2LO;
  } else {
    off = id - 90112u; v = W3[off];
    hi = ws + W3HI; lo = ws + W3LO;
  }
  _Float16 h = (_Float16)v;
  float r = (v - (float)h) * LO_SCALE;
  hi[off] = h;
  lo[off] = (_Float16)r;
}

__global__ __attribute__((amdgpu_waves_per_eu(4, 4)))
__launch_bounds__(1024) void snn_kernel(
    const float* __restrict__ x,
    const float* __restrict__ b1, const float* __restrict__ b2,
    const float* __restrict__ b3, const float* __restrict__ W4,
    const float* __restrict__ b4, const _Float16* __restrict__ ws,
    float* __restrict__ out) {
  // LDS: Wh1 53,248 + xA(8-phase) 53,248 + S(double) 50,688 = 157,184 B.
  __shared__ alignas(16) _Float16 Wh1[256][WP1];
  __shared__ alignas(16) _Float16 xAhi[8][16][XPAD];
  __shared__ alignas(16) _Float16 xAlo[8][16][XPAD];
  __shared__ alignas(16) _Float16 S1[2][16][SPAD];
  __shared__ alignas(16) _Float16 S2[2][16][SPAD];
  __shared__ alignas(16) _Float16 S3[2][16][SPAD];

  const int tid = threadIdx.x;
  const int wave = tid >> 6;
  const int lane = tid & 63;
  const int n16 = lane & 15;
  const int kg = lane >> 4;
  const int wb = blockIdx.x << 4;
  const int nn = (wave << 4) + n16;

  // One-time W1hi -> LDS (48 KB from L2; 3 iterations/thread).
  for (int c = tid; c < 3072; c += 1024) {
    int row = c / 12, w = c % 12;
    *(h8*)&Wh1[row][w * 8] = *(const h8*)(ws + W1HI + row * KP + w * 8);
  }

  // Per-wave row bases for the streamed planes (L2-resident hot set).
  const _Float16* w1l = ws + W1LO + nn * KP;
  const _Float16* w2h = ws + W2HI + nn * NH;
  const _Float16* w2l = ws + W2LO + nn * NH;
  const _Float16* w3h = ws + W3HI + nn * NH;
  const _Float16* w3l = ws + W3LO + nn * NH;

  const float bb1 = b1[nn], bb2 = b2[nn], bb3 = b3[nn];

  // Layer 4 lane roles.
  const int j4 = lane >> 5;
  const int ks4 = (lane & 31) << 3;
  const float* w4p = W4 + j4 * NH + ks4;
  const float bb4 = b4[j4];

  float mem1[4] = {0.f, 0.f, 0.f, 0.f};
  float mem2[4] = {0.f, 0.f, 0.f, 0.f};
  float mem3[4] = {0.f, 0.f, 0.f, 0.f};
  float mem4 = 0.f;

  // Diagonal pipeline: phase p runs L1(t=p), L2(p-1), L3(p-2), L4(p-3).
  for (int p = 0; p < TSTEPS + 3; ++p) {
    const int cur = p & 1;   // S write buffer this phase; read buffer = cur^1
    const bool a1 = (p < TSTEPS);
    const bool a2 = (p >= 1) && (p < TSTEPS + 1);
    const bool a3 = (p >= 2) && (p < TSTEPS + 2);
    const bool a4 = (p >= 3) && (p < TSTEPS + 3);

    if (a1 && (p & 7) == 0) {
      // Stage 8 steps of x (t = p..p+7). Per (m,i): two adjacent f4s = 32 B
      // of one 64 B line; other half consumed next group via L2.
      for (unsigned e = (unsigned)tid; e < 3072u; e += 1024u) {
        unsigned m = e / 192u, r = e % 192u, i = r >> 1, t4 = r & 1u;
        f4 v = {0.f, 0.f, 0.f, 0.f};
        if (i < NIN)
          v = *(const f4*)(x + ((size_t)(wb + m) * NIN + i) * TSTEPS + p +
                           t4 * 4);
#pragma unroll
        for (int s = 0; s < 4; ++s) {
          float f = v[s];
          _Float16 h = (_Float16)f;
          xAhi[t4 * 4 + s][m][i] = h;
          xAlo[t4 * 4 + s][m][i] = (_Float16)((f - (float)h) * LO_SCALE);
        }
      }
      lds_barrier();  // also covers the one-time W1hi LDS fill at p=0
    }

    // ---- issue streamed weight loads early (hidden under L1's LDS MFMAs) --
    h8 w1lo[3];
    if (a1) {
#pragma unroll
      for (int kt = 0; kt < 3; ++kt)
        w1lo[kt] = *(const h8*)(w1l + kt * 32 + kg * 8);
    }
    h8 wl2a[4], wl2b[4];
    if (a2) {
#pragma unroll
      for (int q = 0; q < 4; ++q)
        wl2a[q] = *(const h8*)(w2l + q * 32 + kg * 8);
#pragma unroll
      for (int q = 0; q < 4; ++q)
        wl2b[q] = *(const h8*)(w2l + (4 + q) * 32 + kg * 8);
    }
    h8 wl3a[4], wl3b[4];
    f4 w4a, w4b;
    if (a3) {
#pragma unroll
      for (int q = 0; q < 4; ++q)
        wl3a[q] = *(const h8*)(w3l + q * 32 + kg * 8);
#pragma unroll
      for (int q = 0; q < 4; ++q)
        wl3b[q] = *(const h8*)(w3l + (4 + q) * 32 + kg * 8);
    }
    if (a4) {
      w4a = *(const f4*)(w4p);
      w4b = *(const f4*)(w4p + 4);
    }

    // ---------------- L1 (t = p): xA LDS, W1hi LDS, W1lo streamed --------
    if (a1) {
      const int ph = p & 7;
      f4 aH = {0.f, 0.f, 0.f, 0.f};
      f4 aL = {0.f, 0.f, 0.f, 0.f};
#pragma unroll
      for (int kt = 0; kt < 3; ++kt) {
        const int ko = kt * 32 + kg * 8;
        h8 ahi = *(const h8*)&xAhi[ph][n16][ko];
        h8 alo = *(const h8*)&xAlo[ph][n16][ko];
        h8 wh = *(const h8*)&Wh1[nn][ko];
        aH = __builtin_amdgcn_mfma_f32_16x16x32_f16(ahi, wh, aH, 0, 0, 0);
        aL = __builtin_amdgcn_mfma_f32_16x16x32_f16(alo, wh, aL, 0, 0, 0);
        aL = __builtin_amdgcn_mfma_f32_16x16x32_f16(ahi, w1lo[kt], aL, 0, 0, 0);
      }
#pragma unroll
      for (int r = 0; r < 4; ++r) {
        float cur_ = __fadd_rn(__fadd_rn(aH[r], __fmul_rn(aL[r], LO_INV)), bb1);
        float mo = mem1[r];
        float mn = __fsub_rn(__fadd_rn(__fmul_rn(0.95f, mo), cur_),
                             (mo > 1.0f) ? 1.0f : 0.0f);
        mem1[r] = mn;
        S1[cur][kg * 4 + r][nn] = (mn > 1.0f) ? (_Float16)1.0f : (_Float16)0.0f;
      }
    }

    // ---------------- L2 (t = p-1): reads S1[cur^1] ----------------------
    if (a2) {
      f4 aH = {0.f, 0.f, 0.f, 0.f};
      f4 aL = {0.f, 0.f, 0.f, 0.f};
#pragma unroll
      for (int kt = 0; kt < 8; ++kt) {
        h8 w = *(const h8*)(w2h + kt * 32 + kg * 8);
        h8 a = *(const h8*)&S1[cur ^ 1][n16][kt * 32 + kg * 8];
        aH = __builtin_amdgcn_mfma_f32_16x16x32_f16(a, w, aH, 0, 0, 0);
      }
#pragma unroll
      for (int q = 0; q < 4; ++q) {
        h8 a = *(const h8*)&S1[cur ^ 1][n16][q * 32 + kg * 8];
        aL = __builtin_amdgcn_mfma_f32_16x16x32_f16(a, wl2a[q], aL, 0, 0, 0);
      }
#pragma unroll
      for (int q = 0; q < 4; ++q) {
        h8 a = *(const h8*)&S1[cur ^ 1][n16][(4 + q) * 32 + kg * 8];
        aL = __builtin_amdgcn_mfma_f32_16x16x32_f16(a, wl2b[q], aL, 0, 0, 0);
      }
#pragma unroll
      for (int r = 0; r < 4; ++r) {
        float cur_ = __fadd_rn(__fadd_rn(aH[r], __fmul_rn(aL[r], LO_INV)), bb2);
        float mo = mem2[r];
        float mn = __fsub_rn(__fadd_rn(__fmul_rn(0.95f, mo), cur_),
                             (mo > 1.0f) ? 1.0f : 0.0f);
        mem2[r] = mn;
        S2[cur][kg * 4 + r][nn] = (mn > 1.0f) ? (_Float16)1.0f : (_Float16)0.0f;
      }
    }

    // ---------------- L3 (t = p-2): reads S2[cur^1] ----------------------
    if (a3) {
      f4 aH = {0.f, 0.f, 0.f, 0.f};
      f4 aL = {0.f, 0.f, 0.f, 0.f};
#pragma unroll
      for (int kt = 0; kt < 8; ++kt) {
        h8 w = *(const h8*)(w3h + kt * 32 + kg * 8);
        h8 a = *(const h8*)&S2[cur ^ 1][n16][kt * 32 + kg * 8];
        aH = __builtin_amdgcn_mfma_f32_16x16x32_f16(a, w, aH, 0, 0, 0);
      }
#pragma unroll
      for (int q = 0; q < 4; ++q) {
        h8 a = *(const h8*)&S2[cur ^ 1][n16][q * 32 + kg * 8];
        aL = __builtin_amdgcn_mfma_f32_16x16x32_f16(a, wl3a[q], aL, 0, 0, 0);
      }
#pragma unroll
      for (int q = 0; q < 4; ++q) {
        h8 a = *(const h8*)&S2[cur ^ 1][n16][(4 + q) * 32 + kg * 8];
        aL = __builtin_amdgcn_mfma_f32_16x16x32_f16(a, wl3b[q], aL, 0, 0, 0);
      }
#pragma unroll
      for (int r = 0; r < 4; ++r) {
        float cur_ = __fadd_rn(__fadd_rn(aH[r], __fmul_rn(aL[r], LO_INV)), bb3);
        float mo = mem3[r];
        float mn = __fsub_rn(__fadd_rn(__fmul_rn(0.95f, mo), cur_),
                             (mo > 1.0f) ? 1.0f : 0.0f);
        mem3[r] = mn;
        S3[cur][kg * 4 + r][nn] = (mn > 1.0f) ? (_Float16)1.0f : (_Float16)0.0f;
      }
    }

    // ---------------- L4 (t = p-3): reads S3[cur^1] ----------------------
    if (a4) {
      h8 s = *(const h8*)&S3[cur ^ 1][wave][ks4];
      float pdot = 0.0f;
#pragma unroll
      for (int u = 0; u < 4; ++u)
        pdot = __fadd_rn(pdot, __fmul_rn((float)s[u], w4a[u]));
#pragma unroll
      for (int u = 0; u < 4; ++u)
        pdot = __fadd_rn(pdot, __fmul_rn((float)s[4 + u], w4b[u]));
#pragma unroll
      for (int msk = 1; msk <= 16; msk <<= 1)
        pdot = __fadd_rn(pdot, __shfl_xor(pdot, msk));
      float cur_ = __fadd_rn(pdot, bb4);
      float mo = mem4;
      float mn = __fsub_rn(__fadd_rn(__fmul_rn(0.95f, mo), cur_),
                           (mo > 1.0f) ? 1.0f : 0.0f);
      mem4 = mn;
      if ((lane & 31) == 0)
        out[(size_t)(p - 3) * (BATCH * 2) + (size_t)(wb + wave) * 2 + j4] =
            (mn > 1.0f) ? 1.0f : 0.0f;
    }

    lds_barrier();  // single inter-phase barrier (was 4 per step)
  }
}

extern "C" void kernel_launch(void* const* d_in, const int* in_sizes, int n_in,
                              void* d_out, int out_size, void* d_ws,
                              size_t ws_size, hipStream_t stream) {
  const float* x  = (const float*)d_in[0];
  const float* W1 = (const float*)d_in[1];
  const float* b1 = (const float*)d_in[2];
  const float* W2 = (const float*)d_in[3];
  const float* b2 = (const float*)d_in[4];
  const float* W3 = (const float*)d_in[5];
  const float* b3 = (const float*)d_in[6];
  const float* W4 = (const float*)d_in[7];
  const float* b4 = (const float*)d_in[8];
  float* out = (float*)d_out;
  _Float16* ws = (_Float16*)d_ws;

  hipLaunchKernelGGL(prep_kernel, dim3(608), dim3(256), 0, stream,
                     W1, W2, W3, ws);
  hipLaunchKernelGGL(snn_kernel, dim3(BATCH / 16), dim3(1024), 0, stream,
                     x, b1, b2, b3, W4, b4, ws, out);
}